// Round 5
// baseline (283.392 us; speedup 1.0000x reference)
//
#include <hip/hip_runtime.h>

#define GRID 2048
#define BLK  256
#define NWAVES (BLK / 64)
#define STRIDE (GRID * BLK)

// Native clang vector type.
typedef float floatx4 __attribute__((ext_vector_type(4)));

// d * rcp(den) with v_rcp_f32 (<=1 ulp) — threshold slack is enormous.
__device__ __forceinline__ float frcp(float x) {
    return __builtin_amdgcn_rcpf(x);
}

// Fully-streaming load, single (tail use). sc0 sc1 nt = no-allocate at all
// cache levels; R3 showed NT policy is worth -13 us vs cached, R4 showed
// sc0sc1nt == plain nt (policy lever exhausted).
__device__ __forceinline__ floatx4 stream_load(const floatx4* p) {
    floatx4 r;
    asm volatile("global_load_dwordx4 %0, %1, off sc0 sc1 nt\n\t"
                 "s_waitcnt vmcnt(0)"
                 : "=&v"(r) : "v"(p));
    return r;
}

// MLP=4 streaming load: 4 independent loads in flight before one waitcnt.
// R3/R4's per-load vmcnt(0) forced MLP=1/wave; under loaded-HBM latency
// (~2-3k cy) 32 waves x 1KB outstanding is marginal for 6.3 TB/s — this
// quadruples outstanding bytes per wave. (R2's unroll null was confounded:
// it ran in the cached/dirty-L3 regime where writeback traffic, not MLP,
// was binding.)
__device__ __forceinline__ void stream_load4(
    const floatx4* p0, const floatx4* p1,
    const floatx4* p2, const floatx4* p3,
    floatx4& r0, floatx4& r1, floatx4& r2, floatx4& r3) {
    asm volatile(
        "global_load_dwordx4 %0, %4, off sc0 sc1 nt\n\t"
        "global_load_dwordx4 %1, %5, off sc0 sc1 nt\n\t"
        "global_load_dwordx4 %2, %6, off sc0 sc1 nt\n\t"
        "global_load_dwordx4 %3, %7, off sc0 sc1 nt\n\t"
        "s_waitcnt vmcnt(0)"
        : "=&v"(r0), "=&v"(r1), "=&v"(r2), "=&v"(r3)
        : "v"(p0), "v"(p1), "v"(p2), "v"(p3));
}

__global__ __launch_bounds__(BLK) void pacmap_partial_kernel(
    const floatx4* __restrict__ nb, int n_n,
    const floatx4* __restrict__ mn, int n_m,
    const floatx4* __restrict__ fr, int n_f,
    float* __restrict__ ws) {

    const int tid = blockIdx.x * BLK + threadIdx.x;

    float s_n = 0.0f, s_m = 0.0f, s_f = 0.0f;

    // Bodies keep accumulation in original index order -> bitwise-identical.
    auto near_body = [&](floatx4 p) {
        float dx = p.x - p.z, dy = p.y - p.w;
        float d  = fmaf(dx, dx, fmaf(dy, dy, 1.0f));
        s_n += d * frcp(10.0f + d);
    };
    auto mid_body = [&](floatx4 p) {
        float dx = p.x - p.z, dy = p.y - p.w;
        float d  = fmaf(dx, dx, fmaf(dy, dy, 1.0f));
        s_m += d * frcp(10000.0f + d);
    };
    auto far_body = [&](floatx4 p) {
        float dx = p.x - p.z, dy = p.y - p.w;
        float d  = fmaf(dx, dx, fmaf(dy, dy, 1.0f));
        s_f += frcp(1.0f + d);
    };

    auto do_near = [&]() {
        int i = tid;
        for (; i < n_n - 3 * STRIDE; i += 4 * STRIDE) {
            floatx4 p0, p1, p2, p3;
            stream_load4(&nb[i], &nb[i + STRIDE], &nb[i + 2 * STRIDE], &nb[i + 3 * STRIDE],
                         p0, p1, p2, p3);
            near_body(p0); near_body(p1); near_body(p2); near_body(p3);
        }
        for (; i < n_n; i += STRIDE) near_body(stream_load(&nb[i]));
    };
    auto do_mid = [&]() {
        int i = tid;
        for (; i < n_m - 3 * STRIDE; i += 4 * STRIDE) {
            floatx4 p0, p1, p2, p3;
            stream_load4(&mn[i], &mn[i + STRIDE], &mn[i + 2 * STRIDE], &mn[i + 3 * STRIDE],
                         p0, p1, p2, p3);
            mid_body(p0); mid_body(p1); mid_body(p2); mid_body(p3);
        }
        for (; i < n_m; i += STRIDE) mid_body(stream_load(&mn[i]));
    };
    auto do_far = [&]() {
        int i = tid;
        for (; i < n_f - 3 * STRIDE; i += 4 * STRIDE) {
            floatx4 p0, p1, p2, p3;
            stream_load4(&fr[i], &fr[i + STRIDE], &fr[i + 2 * STRIDE], &fr[i + 3 * STRIDE],
                         p0, p1, p2, p3);
            far_body(p0); far_body(p1); far_body(p2); far_body(p3);
        }
        for (; i < n_f; i += STRIDE) far_body(stream_load(&fr[i]));
    };

    if (blockIdx.x & 1) {
        do_far();
        do_near();
        do_mid();
    } else {
        do_near();
        do_mid();
        do_far();
    }

    // wave-64 shuffle reduction
    #pragma unroll
    for (int off = 32; off > 0; off >>= 1) {
        s_n += __shfl_down(s_n, off, 64);
        s_m += __shfl_down(s_m, off, 64);
        s_f += __shfl_down(s_f, off, 64);
    }

    __shared__ float sm[3][NWAVES];
    const int lane = threadIdx.x & 63;
    const int wid  = threadIdx.x >> 6;
    if (lane == 0) {
        sm[0][wid] = s_n;
        sm[1][wid] = s_m;
        sm[2][wid] = s_f;
    }
    __syncthreads();
    if (threadIdx.x == 0) {
        float a = 0.0f, b = 0.0f, c = 0.0f;
        #pragma unroll
        for (int i = 0; i < NWAVES; ++i) {
            a += sm[0][i];
            b += sm[1][i];
            c += sm[2][i];
        }
        ws[blockIdx.x]            = a;
        ws[GRID + blockIdx.x]     = b;
        ws[2 * GRID + blockIdx.x] = c;
    }
}

// Single-block finalize: reduce GRID partials per loss, apply phase weights.
__global__ __launch_bounds__(BLK) void pacmap_finalize_kernel(
    const float* __restrict__ ws,
    const int* __restrict__ iter_p,
    float* __restrict__ out) {

    float s_n = 0.0f, s_m = 0.0f, s_f = 0.0f;
    for (int i = threadIdx.x; i < GRID; i += BLK) {
        s_n += ws[i];
        s_m += ws[GRID + i];
        s_f += ws[2 * GRID + i];
    }

    #pragma unroll
    for (int off = 32; off > 0; off >>= 1) {
        s_n += __shfl_down(s_n, off, 64);
        s_m += __shfl_down(s_m, off, 64);
        s_f += __shfl_down(s_f, off, 64);
    }

    __shared__ float sm[3][NWAVES];
    const int lane = threadIdx.x & 63;
    const int wid  = threadIdx.x >> 6;
    if (lane == 0) {
        sm[0][wid] = s_n;
        sm[1][wid] = s_m;
        sm[2][wid] = s_f;
    }
    __syncthreads();
    if (threadIdx.x == 0) {
        float a = 0.0f, b = 0.0f, c = 0.0f;
        #pragma unroll
        for (int i = 0; i < NWAVES; ++i) {
            a += sm[0][i];
            b += sm[1][i];
            c += sm[2][i];
        }

        const int it = *iter_p;
        float w_n, w_m, w_f;
        if (it < 101) {
            const float frac = (0.0f - 1.0f) / (101.0f - 1.0f);
            w_n = 2.0f;
            w_m = 1000.0f * (1.0f - frac) + 3.0f * frac;
            w_f = 1.0f;
        } else if (it < 201) {
            w_n = 3.0f; w_m = 3.0f; w_f = 1.0f;
        } else {
            w_n = 1.0f; w_m = 0.0f; w_f = 1.0f;
        }
        out[0] = a * w_n + b * w_m + c * w_f;
    }
}

extern "C" void kernel_launch(void* const* d_in, const int* in_sizes, int n_in,
                              void* d_out, int out_size, void* d_ws, size_t ws_size,
                              hipStream_t stream) {
    const floatx4* nb = (const floatx4*)d_in[0];
    const floatx4* mn = (const floatx4*)d_in[1];
    const floatx4* fr = (const floatx4*)d_in[2];
    const int* iter_p = (const int*)d_in[3];

    const int n_n = in_sizes[0] / 4;
    const int n_m = in_sizes[1] / 4;
    const int n_f = in_sizes[2] / 4;

    float* ws  = (float*)d_ws;
    float* out = (float*)d_out;

    pacmap_partial_kernel<<<GRID, BLK, 0, stream>>>(nb, n_n, mn, n_m, fr, n_f, ws);
    pacmap_finalize_kernel<<<1, BLK, 0, stream>>>(ws, iter_p, out);
}

// Round 7
// 275.051 us; speedup vs baseline: 1.0303x; 1.0303x over previous
//
#include <hip/hip_runtime.h>

#define GRID 2048
#define BLK  256
#define NWAVES (BLK / 64)
#define STRIDE (GRID * BLK)

// Native clang vector type.
typedef float floatx4 __attribute__((ext_vector_type(4)));

// d * rcp(den) with v_rcp_f32 (<=1 ulp) — threshold slack is enormous.
__device__ __forceinline__ float frcp(float x) {
    return __builtin_amdgcn_rcpf(x);
}

// Fully-streaming load: sc0 sc1 nt = no-allocate at every cache level.
// Evidence chain (R0-R5):
//  - The harness's 2x640 MB poison fills leave the 256 MiB Infinity Cache
//    full of dirty lines; cached reads pay a one-writeback-per-line eviction
//    tax (R0/R1 regress when caching more).
//  - NT policy on all three streams removes the controllable share of that
//    tax: -13 us (R3).
//  - sc0 sc1 nt == plain nt (R4 null): policy lever saturated.
//  - MLP=4 regresses (R5): the kernel is bandwidth-bound (mandatory 280 MB
//    reads + fill-side lazy writeback drain), not latency-bound.
// waitcnt bundled inside the asm (separate-waitcnt hoisting hazard, rule #18).
__device__ __forceinline__ floatx4 stream_load(const floatx4* p) {
    floatx4 r;
    asm volatile("global_load_dwordx4 %0, %1, off sc0 sc1 nt\n\t"
                 "s_waitcnt vmcnt(0)"
                 : "=&v"(r) : "v"(p));
    return r;
}

__global__ __launch_bounds__(BLK) void pacmap_partial_kernel(
    const floatx4* __restrict__ nb, int n_n,
    const floatx4* __restrict__ mn, int n_m,
    const floatx4* __restrict__ fr, int n_f,
    float* __restrict__ ws) {

    const int tid = blockIdx.x * BLK + threadIdx.x;

    float s_n = 0.0f, s_m = 0.0f, s_f = 0.0f;

    auto do_near = [&]() {
        for (int i = tid; i < n_n; i += STRIDE) {
            floatx4 p = stream_load(&nb[i]);
            float dx = p.x - p.z, dy = p.y - p.w;
            float d  = fmaf(dx, dx, fmaf(dy, dy, 1.0f));
            s_n += d * frcp(10.0f + d);
        }
    };
    auto do_mid = [&]() {
        for (int i = tid; i < n_m; i += STRIDE) {
            floatx4 p = stream_load(&mn[i]);
            float dx = p.x - p.z, dy = p.y - p.w;
            float d  = fmaf(dx, dx, fmaf(dy, dy, 1.0f));
            s_m += d * frcp(10000.0f + d);
        }
    };
    auto do_far = [&]() {
        for (int i = tid; i < n_f; i += STRIDE) {
            floatx4 p = stream_load(&fr[i]);
            float dx = p.x - p.z, dy = p.y - p.w;
            float d  = fmaf(dx, dx, fmaf(dy, dy, 1.0f));
            s_f += frcp(1.0f + d);
        }
    };

    if (blockIdx.x & 1) {
        do_far();
        do_near();
        do_mid();
    } else {
        do_near();
        do_mid();
        do_far();
    }

    // wave-64 shuffle reduction
    #pragma unroll
    for (int off = 32; off > 0; off >>= 1) {
        s_n += __shfl_down(s_n, off, 64);
        s_m += __shfl_down(s_m, off, 64);
        s_f += __shfl_down(s_f, off, 64);
    }

    __shared__ float sm[3][NWAVES];
    const int lane = threadIdx.x & 63;
    const int wid  = threadIdx.x >> 6;
    if (lane == 0) {
        sm[0][wid] = s_n;
        sm[1][wid] = s_m;
        sm[2][wid] = s_f;
    }
    __syncthreads();
    if (threadIdx.x == 0) {
        float a = 0.0f, b = 0.0f, c = 0.0f;
        #pragma unroll
        for (int i = 0; i < NWAVES; ++i) {
            a += sm[0][i];
            b += sm[1][i];
            c += sm[2][i];
        }
        ws[blockIdx.x]            = a;
        ws[GRID + blockIdx.x]     = b;
        ws[2 * GRID + blockIdx.x] = c;
    }
}

// Single-block finalize: reduce GRID partials per loss, apply phase weights.
__global__ __launch_bounds__(BLK) void pacmap_finalize_kernel(
    const float* __restrict__ ws,
    const int* __restrict__ iter_p,
    float* __restrict__ out) {

    float s_n = 0.0f, s_m = 0.0f, s_f = 0.0f;
    for (int i = threadIdx.x; i < GRID; i += BLK) {
        s_n += ws[i];
        s_m += ws[GRID + i];
        s_f += ws[2 * GRID + i];
    }

    #pragma unroll
    for (int off = 32; off > 0; off >>= 1) {
        s_n += __shfl_down(s_n, off, 64);
        s_m += __shfl_down(s_m, off, 64);
        s_f += __shfl_down(s_f, off, 64);
    }

    __shared__ float sm[3][NWAVES];
    const int lane = threadIdx.x & 63;
    const int wid  = threadIdx.x >> 6;
    if (lane == 0) {
        sm[0][wid] = s_n;
        sm[1][wid] = s_m;
        sm[2][wid] = s_f;
    }
    __syncthreads();
    if (threadIdx.x == 0) {
        float a = 0.0f, b = 0.0f, c = 0.0f;
        #pragma unroll
        for (int i = 0; i < NWAVES; ++i) {
            a += sm[0][i];
            b += sm[1][i];
            c += sm[2][i];
        }

        const int it = *iter_p;
        float w_n, w_m, w_f;
        if (it < 101) {
            const float frac = (0.0f - 1.0f) / (101.0f - 1.0f);
            w_n = 2.0f;
            w_m = 1000.0f * (1.0f - frac) + 3.0f * frac;
            w_f = 1.0f;
        } else if (it < 201) {
            w_n = 3.0f; w_m = 3.0f; w_f = 1.0f;
        } else {
            w_n = 1.0f; w_m = 0.0f; w_f = 1.0f;
        }
        out[0] = a * w_n + b * w_m + c * w_f;
    }
}

extern "C" void kernel_launch(void* const* d_in, const int* in_sizes, int n_in,
                              void* d_out, int out_size, void* d_ws, size_t ws_size,
                              hipStream_t stream) {
    const floatx4* nb = (const floatx4*)d_in[0];
    const floatx4* mn = (const floatx4*)d_in[1];
    const floatx4* fr = (const floatx4*)d_in[2];
    const int* iter_p = (const int*)d_in[3];

    const int n_n = in_sizes[0] / 4;
    const int n_m = in_sizes[1] / 4;
    const int n_f = in_sizes[2] / 4;

    float* ws  = (float*)d_ws;
    float* out = (float*)d_out;

    pacmap_partial_kernel<<<GRID, BLK, 0, stream>>>(nb, n_n, mn, n_m, fr, n_f, ws);
    pacmap_finalize_kernel<<<1, BLK, 0, stream>>>(ws, iter_p, out);
}